// Round 3
// baseline (531.443 us; speedup 1.0000x reference)
//
#include <hip/hip_runtime.h>
#include <hip/hip_bf16.h>

#define N_NODES 50000
#define N_EDGES 600000
#define GEMM_BLOCKS 512   // 256-thread blocks, 8 rows/iter -> 1024 stat partials

// ---- workspace layout (bytes) ----
#define AGG_OFF      0ull           // float[50000*128]  (fully written by k_gather)
#define DEGO_OFF     25600000ull    // int[50000]  (zeroed)
#define DEGI_OFF     25800000ull    // int[50000]  (zeroed)
#define CURS_OFF     26000000ull    // int[50000]  (zeroed)
#define ZERO_OFF     25600000ull
#define ZERO_BYTES   600000ull
#define FLAG_OFF     26200000ull    // int[1] (written by k_detect)
#define ROWS_OFF     26200064ull    // int[50001]
#define ESRC_OFF     26400128ull    // int[600000]
#define RSQO_OFF     28800128ull    // float[50000]
#define RSQI_OFF     29000128ull    // float[50000]
#define PSUM_OFF     29200192ull    // float[1024*128]
#define PSQ_OFF      29724480ull    // float[1024*128]
#define SCALE_OFF    30248768ull    // float[128]
#define SHIFT_OFF    30249280ull    // float[128]
#define OUTPRE_OFF   33554432ull    // float[50000*128]

__device__ __forceinline__ float bf16lo(unsigned int v) { return __uint_as_float(v << 16); }
__device__ __forceinline__ float bf16hi(unsigned int v) { return __uint_as_float(v & 0xffff0000u); }

// ---------------- dtype detect: bf16-packed vs fp32 ----------------
// For bf16 h~N(0,1): bits[14:7] of each dword's LOW half are a bf16 exponent
// (~113..129). For fp32 h: those are uniform mantissa bits (~16% in window).
__global__ __launch_bounds__(256) void k_detect(const unsigned int* __restrict__ hu,
                                                int* __restrict__ flag) {
  __shared__ int cnt;
  if (threadIdx.x == 0) cnt = 0;
  __syncthreads();
  unsigned int u = hu[threadIdx.x];
  int e = (u >> 7) & 0xFF;
  if (e >= 100 && e <= 140) atomicAdd(&cnt, 1);
  __syncthreads();
  if (threadIdx.x == 0) *flag = (cnt >= 128) ? 1 : 0;  // 1 = bf16, 0 = fp32
}

// ---------------- degrees (int atomics only) ----------------
__global__ __launch_bounds__(256) void k_deg(const int* __restrict__ src,
                                             const int* __restrict__ dst,
                                             int* __restrict__ dego,
                                             int* __restrict__ degi) {
  int e = blockIdx.x * 256 + threadIdx.x;
  if (e < N_EDGES) {
    atomicAdd(&dego[src[e]], 1);
    atomicAdd(&degi[dst[e]], 1);
  }
}

// ---------------- exclusive scan of degi -> row_start; rsq tables ----------
__global__ __launch_bounds__(1024) void k_scan(const int* __restrict__ dego,
                                               const int* __restrict__ degi,
                                               int* __restrict__ row_start,
                                               float* __restrict__ rsqo,
                                               float* __restrict__ rsqi) {
  __shared__ int ls[1024];
  const int CH = 49;  // 1024*49 >= 50000
  int t = threadIdx.x;
  int lo = t * CH;
  int hi = lo + CH; if (hi > N_NODES) hi = N_NODES;
  if (lo > N_NODES) lo = N_NODES;
  int s = 0;
  for (int i = lo; i < hi; ++i) s += degi[i];
  ls[t] = s;
  __syncthreads();
  for (int off = 1; off < 1024; off <<= 1) {
    int v = 0;
    if (t >= off) v = ls[t - off];
    __syncthreads();
    if (t >= off) ls[t] += v;
    __syncthreads();
  }
  int excl = (t == 0) ? 0 : ls[t - 1];
  for (int i = lo; i < hi; ++i) {
    row_start[i] = excl;
    int di = degi[i];
    excl += di;
    int doo = dego[i];
    rsqi[i] = rsqrtf((float)(di  < 1 ? 1 : di));
    rsqo[i] = rsqrtf((float)(doo < 1 ? 1 : doo));
  }
  if (t == 1023) row_start[N_NODES] = ls[1023];
}

// ---------------- CSR fill (int atomics only) ----------------
__global__ __launch_bounds__(256) void k_fill(const int* __restrict__ src,
                                              const int* __restrict__ dst,
                                              const int* __restrict__ row_start,
                                              int* __restrict__ cursor,
                                              int* __restrict__ esrc) {
  int e = blockIdx.x * 256 + threadIdx.x;
  if (e < N_EDGES) {
    int d = dst[e];
    int slot = atomicAdd(&cursor[d], 1);
    esrc[row_start[d] + slot] = src[e];
  }
}

// ---------------- gather: agg[n] = rsqi[n] * sum_e h[src_e]*rsqo[src_e] ----
// one wave per node; lane l covers features 2l, 2l+1
__global__ __launch_bounds__(256) void k_gather(const void* __restrict__ hraw,
                                                const int* __restrict__ row_start,
                                                const int* __restrict__ esrc,
                                                const float* __restrict__ rsqo,
                                                const float* __restrict__ rsqi,
                                                const int* __restrict__ flag,
                                                float* __restrict__ agg) {
  int n = blockIdx.x * 4 + (threadIdx.x >> 6);   // grid = N_NODES/4 exactly
  int l = threadIdx.x & 63;
  int jb = row_start[n];
  int je = row_start[n + 1];
  float a0 = 0.f, a1 = 0.f;
  if (*flag) {
    const unsigned int* hu = (const unsigned int*)hraw;
    for (int j = jb; j < je; ++j) {
      int s = esrc[j];
      float c = rsqo[s];
      unsigned int v = hu[(size_t)s * 64 + l];
      a0 += bf16lo(v) * c;
      a1 += bf16hi(v) * c;
    }
  } else {
    const float2* hf = (const float2*)hraw;
    for (int j = jb; j < je; ++j) {
      int s = esrc[j];
      float c = rsqo[s];
      float2 v = hf[(size_t)s * 64 + l];
      a0 += v.x * c;
      a1 += v.y * c;
    }
  }
  float scn = rsqi[n];
  float2 o; o.x = a0 * scn; o.y = a1 * scn;
  *(float2*)&agg[(size_t)n * 128 + 2 * l] = o;
}

// ---------------- GEMM: outpre = agg @ W, + BN per-block partial stats ------
__global__ __launch_bounds__(256) void k_gemm(const float* __restrict__ agg,
                                              const void* __restrict__ Wraw,
                                              const int* __restrict__ flag,
                                              float* __restrict__ outpre,
                                              float* __restrict__ psum,
                                              float* __restrict__ psq) {
  __shared__ float lw[128 * 128];   // W as f32 [k][c]  (64 KB)
  __shared__ float la[8 * 128];     // 8 staged rows    (4 KB)
  int t = threadIdx.x;
  if (*flag) {
    const unsigned int* Wd = (const unsigned int*)Wraw;   // bf16 pairs
    for (int i = t; i < 8192; i += 256) {
      unsigned int v = Wd[i];
      lw[2 * i]     = bf16lo(v);
      lw[2 * i + 1] = bf16hi(v);
    }
  } else {
    const float* Wf = (const float*)Wraw;
    for (int i = t; i < 16384; i += 256) lw[i] = Wf[i];
  }
  __syncthreads();

  int c    = t & 127;   // output column
  int half = t >> 7;    // 0..1 -> rows rb..rb+3
  int rb   = half * 4;
  float s1 = 0.f, s2 = 0.f;

  for (int r0 = blockIdx.x * 8; r0 < N_NODES; r0 += GEMM_BLOCKS * 8) {
    { // stage 8 rows of agg
      int jr = t >> 5;            // 0..7
      int k4 = (t & 31) * 4;
      *(float4*)&la[jr * 128 + k4] = *(const float4*)&agg[(size_t)(r0 + jr) * 128 + k4];
    }
    __syncthreads();

    float acc0 = 0.f, acc1 = 0.f, acc2 = 0.f, acc3 = 0.f;
#pragma unroll 4
    for (int k = 0; k < 128; k += 4) {
      float4 a0 = *(const float4*)&la[(rb + 0) * 128 + k];
      float4 a1 = *(const float4*)&la[(rb + 1) * 128 + k];
      float4 a2 = *(const float4*)&la[(rb + 2) * 128 + k];
      float4 a3 = *(const float4*)&la[(rb + 3) * 128 + k];
      float w0 = lw[(k + 0) * 128 + c];
      float w1 = lw[(k + 1) * 128 + c];
      float w2 = lw[(k + 2) * 128 + c];
      float w3 = lw[(k + 3) * 128 + c];
      acc0 += a0.x * w0 + a0.y * w1 + a0.z * w2 + a0.w * w3;
      acc1 += a1.x * w0 + a1.y * w1 + a1.z * w2 + a1.w * w3;
      acc2 += a2.x * w0 + a2.y * w1 + a2.z * w2 + a2.w * w3;
      acc3 += a3.x * w0 + a3.y * w1 + a3.z * w2 + a3.w * w3;
    }
    outpre[(size_t)(r0 + rb + 0) * 128 + c] = acc0;
    outpre[(size_t)(r0 + rb + 1) * 128 + c] = acc1;
    outpre[(size_t)(r0 + rb + 2) * 128 + c] = acc2;
    outpre[(size_t)(r0 + rb + 3) * 128 + c] = acc3;
    s1 += acc0 + acc1 + acc2 + acc3;
    s2 += acc0 * acc0 + acc1 * acc1 + acc2 * acc2 + acc3 * acc3;
    __syncthreads();
  }
  psum[(blockIdx.x * 2 + half) * 128 + c] = s1;
  psq [(blockIdx.x * 2 + half) * 128 + c] = s2;
}

// ---------------- BN finalize: reduce 1024 partials -> scale/shift ----------
__global__ __launch_bounds__(1024) void k_bnfinal(const float* __restrict__ psum,
                                                  const float* __restrict__ psq,
                                                  const void* __restrict__ gamma,
                                                  const void* __restrict__ beta,
                                                  const int* __restrict__ flag,
                                                  float* __restrict__ scale,
                                                  float* __restrict__ shift) {
  __shared__ float r1[1024], r2[1024];
  int t = threadIdx.x;
  int c = t & 127;
  int j = t >> 7;           // 0..7
  float s1 = 0.f, s2 = 0.f;
  for (int b = j; b < GEMM_BLOCKS * 2; b += 8) {
    s1 += psum[b * 128 + c];
    s2 += psq [b * 128 + c];
  }
  r1[t] = s1; r2[t] = s2;
  __syncthreads();
  if (j == 0) {
#pragma unroll
    for (int jj = 1; jj < 8; ++jj) { s1 += r1[c + 128 * jj]; s2 += r2[c + 128 * jj]; }
    const float invN = 1.0f / (float)N_NODES;
    float mu  = s1 * invN;
    float var = s2 * invN - mu * mu;
    float is  = rsqrtf(var + 1e-5f);
    float g, b;
    if (*flag) {
      g = __bfloat162float(((const __hip_bfloat16*)gamma)[c]);
      b = __bfloat162float(((const __hip_bfloat16*)beta)[c]);
    } else {
      g = ((const float*)gamma)[c];
      b = ((const float*)beta)[c];
    }
    scale[c] = g * is;
    shift[c] = b - mu * g * is;
  }
}

// ---------------- BN apply + ReLU + row L2 normalize + store ----------------
__global__ __launch_bounds__(256) void k_rownorm(const float* __restrict__ outpre,
                                                 const float* __restrict__ scale,
                                                 const float* __restrict__ shift,
                                                 const int* __restrict__ flag,
                                                 void* __restrict__ outraw) {
  int r = blockIdx.x * 4 + (threadIdx.x >> 6);   // grid = N_NODES/4 exactly
  int l = threadIdx.x & 63;
  float2 x  = *(const float2*)&outpre[(size_t)r * 128 + 2 * l];
  float2 sc = *(const float2*)&scale[2 * l];
  float2 sh = *(const float2*)&shift[2 * l];
  float y0 = fmaxf(x.x * sc.x + sh.x, 0.f);
  float y1 = fmaxf(x.y * sc.y + sh.y, 0.f);
  float ss = y0 * y0 + y1 * y1;
#pragma unroll
  for (int o = 1; o < 64; o <<= 1) ss += __shfl_xor(ss, o, 64);
  float inv = 1.0f / fmaxf(sqrtf(ss), 1e-12f);
  y0 *= inv; y1 *= inv;
  if (*flag) {
    __hip_bfloat162 o2;
    o2.x = __float2bfloat16(y0);
    o2.y = __float2bfloat16(y1);
    union { __hip_bfloat162 v; unsigned int u; } cvt;
    cvt.v = o2;
    ((unsigned int*)outraw)[(size_t)r * 64 + l] = cvt.u;
  } else {
    float2 o2; o2.x = y0; o2.y = y1;
    ((float2*)outraw)[(size_t)r * 64 + l] = o2;
  }
}

extern "C" void kernel_launch(void* const* d_in, const int* in_sizes, int n_in,
                              void* d_out, int out_size, void* d_ws, size_t ws_size,
                              hipStream_t stream) {
  const void* h     = d_in[0];
  const void* W     = d_in[1];
  const void* gamma = d_in[2];
  const void* beta  = d_in[3];
  const int*  src   = (const int*)d_in[4];
  const int*  dst   = (const int*)d_in[5];

  char* ws = (char*)d_ws;
  float* agg    = (float*)(ws + AGG_OFF);
  int*   dego   = (int*)(ws + DEGO_OFF);
  int*   degi   = (int*)(ws + DEGI_OFF);
  int*   cursor = (int*)(ws + CURS_OFF);
  int*   flag   = (int*)(ws + FLAG_OFF);
  int*   rows   = (int*)(ws + ROWS_OFF);
  int*   esrc   = (int*)(ws + ESRC_OFF);
  float* rsqo   = (float*)(ws + RSQO_OFF);
  float* rsqi   = (float*)(ws + RSQI_OFF);
  float* psum   = (float*)(ws + PSUM_OFF);
  float* psq    = (float*)(ws + PSQ_OFF);
  float* scale  = (float*)(ws + SCALE_OFF);
  float* shift  = (float*)(ws + SHIFT_OFF);
  float* outpre = (float*)(ws + OUTPRE_OFF);

  hipMemsetAsync(ws + ZERO_OFF, 0, ZERO_BYTES, stream);

  hipLaunchKernelGGL(k_detect, dim3(1), dim3(256), 0, stream,
                     (const unsigned int*)h, flag);
  hipLaunchKernelGGL(k_deg, dim3((N_EDGES + 255) / 256), dim3(256), 0, stream,
                     src, dst, dego, degi);
  hipLaunchKernelGGL(k_scan, dim3(1), dim3(1024), 0, stream,
                     dego, degi, rows, rsqo, rsqi);
  hipLaunchKernelGGL(k_fill, dim3((N_EDGES + 255) / 256), dim3(256), 0, stream,
                     src, dst, rows, cursor, esrc);
  hipLaunchKernelGGL(k_gather, dim3(N_NODES / 4), dim3(256), 0, stream,
                     h, rows, esrc, rsqo, rsqi, flag, agg);
  hipLaunchKernelGGL(k_gemm, dim3(GEMM_BLOCKS), dim3(256), 0, stream,
                     agg, W, flag, outpre, psum, psq);
  hipLaunchKernelGGL(k_bnfinal, dim3(1), dim3(1024), 0, stream,
                     psum, psq, gamma, beta, flag, scale, shift);
  hipLaunchKernelGGL(k_rownorm, dim3(N_NODES / 4), dim3(256), 0, stream,
                     outpre, scale, shift, flag, (unsigned int*)d_out);
}

// Round 4
// 355.173 us; speedup vs baseline: 1.4963x; 1.4963x over previous
//
#include <hip/hip_runtime.h>
#include <hip/hip_bf16.h>

#define N_NODES 50000
#define N_EDGES 600000
#define GEMM_BLOCKS 512   // 256-thread blocks, 8 rows/iter -> 1024 stat partials
#define SCAN_BLOCKS 196   // 196*256 = 50176 >= 50000

// ---- workspace layout (bytes) ----
#define AGG_OFF      0ull           // float[50000*128]  (fully written by k_gather)
#define DEGO_OFF     25600000ull    // int[50000]  (zeroed)
#define DEGI_OFF     25800000ull    // int[50000]  (zeroed)
#define CURS_OFF     26000000ull    // int[50000]  (zeroed)
#define ZERO_OFF     25600000ull
#define ZERO_BYTES   600000ull
#define FLAG_OFF     26200000ull    // int[1] (written by k_detect)
#define ROWS_OFF     26200064ull    // int[50001]
#define ESRC_OFF     26400128ull    // int[600000]
#define RSQO_OFF     28800128ull    // float[50000]
#define RSQI_OFF     29000128ull    // float[50000]
#define PSUM_OFF     29200192ull    // float[1024*128]
#define PSQ_OFF      29724480ull    // float[1024*128]
#define SCALE_OFF    30248768ull    // float[128]
#define SHIFT_OFF    30249280ull    // float[128]
#define PEX_OFF      30249792ull    // int[50176]
#define BOFF_OFF     30450496ull    // int[256]
#define OUTPRE_OFF   33554432ull    // float[50000*128]

__device__ __forceinline__ float bf16lo(unsigned int v) { return __uint_as_float(v << 16); }
__device__ __forceinline__ float bf16hi(unsigned int v) { return __uint_as_float(v & 0xffff0000u); }

// ---------------- dtype detect: bf16-packed vs fp32 ----------------
__global__ __launch_bounds__(256) void k_detect(const unsigned int* __restrict__ hu,
                                                int* __restrict__ flag) {
  __shared__ int cnt;
  if (threadIdx.x == 0) cnt = 0;
  __syncthreads();
  unsigned int u = hu[threadIdx.x];
  int e = (u >> 7) & 0xFF;
  if (e >= 100 && e <= 140) atomicAdd(&cnt, 1);
  __syncthreads();
  if (threadIdx.x == 0) *flag = (cnt >= 128) ? 1 : 0;  // 1 = bf16, 0 = fp32
}

// ---------------- degrees (int atomics only) ----------------
__global__ __launch_bounds__(256) void k_deg(const int* __restrict__ src,
                                             const int* __restrict__ dst,
                                             int* __restrict__ dego,
                                             int* __restrict__ degi) {
  int e = blockIdx.x * 256 + threadIdx.x;
  if (e < N_EDGES) {
    atomicAdd(&dego[src[e]], 1);
    atomicAdd(&degi[dst[e]], 1);
  }
}

// ---------------- scan stage 1: intra-block exclusive prefix + block sums ---
// also emits rsqo/rsqi tables
__global__ __launch_bounds__(256) void k_scan1(const int* __restrict__ dego,
                                               const int* __restrict__ degi,
                                               int* __restrict__ pex,
                                               int* __restrict__ bsum,
                                               float* __restrict__ rsqo,
                                               float* __restrict__ rsqi) {
  __shared__ int ls[256];
  int t = threadIdx.x;
  int n = blockIdx.x * 256 + t;
  int d = (n < N_NODES) ? degi[n] : 0;
  ls[t] = d;
  __syncthreads();
#pragma unroll
  for (int off = 1; off < 256; off <<= 1) {
    int v = (t >= off) ? ls[t - off] : 0;
    __syncthreads();
    ls[t] += v;
    __syncthreads();
  }
  int incl = ls[t];
  if (n < N_NODES) {
    pex[n] = incl - d;
    int doo = dego[n];
    rsqi[n] = rsqrtf((float)(d   < 1 ? 1 : d));
    rsqo[n] = rsqrtf((float)(doo < 1 ? 1 : doo));
  }
  if (t == 255) bsum[blockIdx.x] = incl;
}

// ---------------- scan stage 2: scan of block sums ----------------
__global__ __launch_bounds__(256) void k_scan2(const int* __restrict__ bsum,
                                               int* __restrict__ boff) {
  __shared__ int ls[256];
  int t = threadIdx.x;
  int d = (t < SCAN_BLOCKS) ? bsum[t] : 0;
  ls[t] = d;
  __syncthreads();
#pragma unroll
  for (int off = 1; off < 256; off <<= 1) {
    int v = (t >= off) ? ls[t - off] : 0;
    __syncthreads();
    ls[t] += v;
    __syncthreads();
  }
  boff[t] = ls[t] - d;
}

// ---------------- scan stage 3: row_start = pex + boff ----------------
__global__ __launch_bounds__(256) void k_scan3(const int* __restrict__ pex,
                                               const int* __restrict__ boff,
                                               int* __restrict__ row_start) {
  int t = threadIdx.x;
  int n = blockIdx.x * 256 + t;
  if (n < N_NODES) row_start[n] = pex[n] + boff[blockIdx.x];
  if (n == 0) row_start[N_NODES] = N_EDGES;
}

// ---------------- CSR fill (int atomics only) ----------------
__global__ __launch_bounds__(256) void k_fill(const int* __restrict__ src,
                                              const int* __restrict__ dst,
                                              const int* __restrict__ row_start,
                                              int* __restrict__ cursor,
                                              int* __restrict__ esrc) {
  int e = blockIdx.x * 256 + threadIdx.x;
  if (e < N_EDGES) {
    int d = dst[e];
    int slot = atomicAdd(&cursor[d], 1);
    esrc[row_start[d] + slot] = src[e];
  }
}

// ---------------- gather: agg[n] = rsqi[n] * sum_e h[src_e]*rsqo[src_e] ----
__global__ __launch_bounds__(256) void k_gather(const void* __restrict__ hraw,
                                                const int* __restrict__ row_start,
                                                const int* __restrict__ esrc,
                                                const float* __restrict__ rsqo,
                                                const float* __restrict__ rsqi,
                                                const int* __restrict__ flag,
                                                float* __restrict__ agg) {
  int n = blockIdx.x * 4 + (threadIdx.x >> 6);   // grid = N_NODES/4 exactly
  int l = threadIdx.x & 63;
  int jb = row_start[n];
  int je = row_start[n + 1];
  float a0 = 0.f, a1 = 0.f;
  if (*flag) {
    const unsigned int* hu = (const unsigned int*)hraw;
    for (int j = jb; j < je; ++j) {
      int s = esrc[j];
      float c = rsqo[s];
      unsigned int v = hu[(size_t)s * 64 + l];
      a0 += bf16lo(v) * c;
      a1 += bf16hi(v) * c;
    }
  } else {
    const float2* hf = (const float2*)hraw;
    for (int j = jb; j < je; ++j) {
      int s = esrc[j];
      float c = rsqo[s];
      float2 v = hf[(size_t)s * 64 + l];
      a0 += v.x * c;
      a1 += v.y * c;
    }
  }
  float scn = rsqi[n];
  float2 o; o.x = a0 * scn; o.y = a1 * scn;
  *(float2*)&agg[(size_t)n * 128 + 2 * l] = o;
}

// ---------------- GEMM: outpre = agg @ W, + BN per-block partial stats ------
__global__ __launch_bounds__(256) void k_gemm(const float* __restrict__ agg,
                                              const void* __restrict__ Wraw,
                                              const int* __restrict__ flag,
                                              float* __restrict__ outpre,
                                              float* __restrict__ psum,
                                              float* __restrict__ psq) {
  __shared__ float lw[128 * 128];   // W as f32 [k][c]  (64 KB)
  __shared__ float la[8 * 128];     // 8 staged rows    (4 KB)
  int t = threadIdx.x;
  if (*flag) {
    const unsigned int* Wd = (const unsigned int*)Wraw;   // bf16 pairs
    for (int i = t; i < 8192; i += 256) {
      unsigned int v = Wd[i];
      lw[2 * i]     = bf16lo(v);
      lw[2 * i + 1] = bf16hi(v);
    }
  } else {
    const float* Wf = (const float*)Wraw;
    for (int i = t; i < 16384; i += 256) lw[i] = Wf[i];
  }
  __syncthreads();

  int c    = t & 127;   // output column
  int half = t >> 7;    // 0..1 -> rows rb..rb+3
  int rb   = half * 4;
  float s1 = 0.f, s2 = 0.f;

  for (int r0 = blockIdx.x * 8; r0 < N_NODES; r0 += GEMM_BLOCKS * 8) {
    { // stage 8 rows of agg
      int jr = t >> 5;            // 0..7
      int k4 = (t & 31) * 4;
      *(float4*)&la[jr * 128 + k4] = *(const float4*)&agg[(size_t)(r0 + jr) * 128 + k4];
    }
    __syncthreads();

    float acc0 = 0.f, acc1 = 0.f, acc2 = 0.f, acc3 = 0.f;
#pragma unroll 4
    for (int k = 0; k < 128; k += 4) {
      float4 a0 = *(const float4*)&la[(rb + 0) * 128 + k];
      float4 a1 = *(const float4*)&la[(rb + 1) * 128 + k];
      float4 a2 = *(const float4*)&la[(rb + 2) * 128 + k];
      float4 a3 = *(const float4*)&la[(rb + 3) * 128 + k];
      float w0 = lw[(k + 0) * 128 + c];
      float w1 = lw[(k + 1) * 128 + c];
      float w2 = lw[(k + 2) * 128 + c];
      float w3 = lw[(k + 3) * 128 + c];
      acc0 += a0.x * w0 + a0.y * w1 + a0.z * w2 + a0.w * w3;
      acc1 += a1.x * w0 + a1.y * w1 + a1.z * w2 + a1.w * w3;
      acc2 += a2.x * w0 + a2.y * w1 + a2.z * w2 + a2.w * w3;
      acc3 += a3.x * w0 + a3.y * w1 + a3.z * w2 + a3.w * w3;
    }
    outpre[(size_t)(r0 + rb + 0) * 128 + c] = acc0;
    outpre[(size_t)(r0 + rb + 1) * 128 + c] = acc1;
    outpre[(size_t)(r0 + rb + 2) * 128 + c] = acc2;
    outpre[(size_t)(r0 + rb + 3) * 128 + c] = acc3;
    s1 += acc0 + acc1 + acc2 + acc3;
    s2 += acc0 * acc0 + acc1 * acc1 + acc2 * acc2 + acc3 * acc3;
    __syncthreads();
  }
  psum[(blockIdx.x * 2 + half) * 128 + c] = s1;
  psq [(blockIdx.x * 2 + half) * 128 + c] = s2;
}

// ---------------- BN finalize: reduce 1024 partials -> scale/shift ----------
__global__ __launch_bounds__(1024) void k_bnfinal(const float* __restrict__ psum,
                                                  const float* __restrict__ psq,
                                                  const void* __restrict__ gamma,
                                                  const void* __restrict__ beta,
                                                  const int* __restrict__ flag,
                                                  float* __restrict__ scale,
                                                  float* __restrict__ shift) {
  __shared__ float r1[1024], r2[1024];
  int t = threadIdx.x;
  int c = t & 127;
  int j = t >> 7;           // 0..7
  float s1 = 0.f, s2 = 0.f;
  for (int b = j; b < GEMM_BLOCKS * 2; b += 8) {
    s1 += psum[b * 128 + c];
    s2 += psq [b * 128 + c];
  }
  r1[t] = s1; r2[t] = s2;
  __syncthreads();
  if (j == 0) {
#pragma unroll
    for (int jj = 1; jj < 8; ++jj) { s1 += r1[c + 128 * jj]; s2 += r2[c + 128 * jj]; }
    const float invN = 1.0f / (float)N_NODES;
    float mu  = s1 * invN;
    float var = s2 * invN - mu * mu;
    float is  = rsqrtf(var + 1e-5f);
    float g, b;
    if (*flag) {
      g = __bfloat162float(((const __hip_bfloat16*)gamma)[c]);
      b = __bfloat162float(((const __hip_bfloat16*)beta)[c]);
    } else {
      g = ((const float*)gamma)[c];
      b = ((const float*)beta)[c];
    }
    scale[c] = g * is;
    shift[c] = b - mu * g * is;
  }
}

// ---------------- BN apply + ReLU + row L2 normalize + store ----------------
__global__ __launch_bounds__(256) void k_rownorm(const float* __restrict__ outpre,
                                                 const float* __restrict__ scale,
                                                 const float* __restrict__ shift,
                                                 const int* __restrict__ flag,
                                                 void* __restrict__ outraw) {
  int r = blockIdx.x * 4 + (threadIdx.x >> 6);   // grid = N_NODES/4 exactly
  int l = threadIdx.x & 63;
  float2 x  = *(const float2*)&outpre[(size_t)r * 128 + 2 * l];
  float2 sc = *(const float2*)&scale[2 * l];
  float2 sh = *(const float2*)&shift[2 * l];
  float y0 = fmaxf(x.x * sc.x + sh.x, 0.f);
  float y1 = fmaxf(x.y * sc.y + sh.y, 0.f);
  float ss = y0 * y0 + y1 * y1;
#pragma unroll
  for (int o = 1; o < 64; o <<= 1) ss += __shfl_xor(ss, o, 64);
  float inv = 1.0f / fmaxf(sqrtf(ss), 1e-12f);
  y0 *= inv; y1 *= inv;
  if (*flag) {
    __hip_bfloat162 o2;
    o2.x = __float2bfloat16(y0);
    o2.y = __float2bfloat16(y1);
    union { __hip_bfloat162 v; unsigned int u; } cvt;
    cvt.v = o2;
    ((unsigned int*)outraw)[(size_t)r * 64 + l] = cvt.u;
  } else {
    float2 o2; o2.x = y0; o2.y = y1;
    ((float2*)outraw)[(size_t)r * 64 + l] = o2;
  }
}

extern "C" void kernel_launch(void* const* d_in, const int* in_sizes, int n_in,
                              void* d_out, int out_size, void* d_ws, size_t ws_size,
                              hipStream_t stream) {
  const void* h     = d_in[0];
  const void* W     = d_in[1];
  const void* gamma = d_in[2];
  const void* beta  = d_in[3];
  const int*  src   = (const int*)d_in[4];
  const int*  dst   = (const int*)d_in[5];

  char* ws = (char*)d_ws;
  float* agg    = (float*)(ws + AGG_OFF);
  int*   dego   = (int*)(ws + DEGO_OFF);
  int*   degi   = (int*)(ws + DEGI_OFF);
  int*   cursor = (int*)(ws + CURS_OFF);
  int*   flag   = (int*)(ws + FLAG_OFF);
  int*   rows   = (int*)(ws + ROWS_OFF);
  int*   esrc   = (int*)(ws + ESRC_OFF);
  float* rsqo   = (float*)(ws + RSQO_OFF);
  float* rsqi   = (float*)(ws + RSQI_OFF);
  float* psum   = (float*)(ws + PSUM_OFF);
  float* psq    = (float*)(ws + PSQ_OFF);
  float* scale  = (float*)(ws + SCALE_OFF);
  float* shift  = (float*)(ws + SHIFT_OFF);
  int*   pex    = (int*)(ws + PEX_OFF);
  int*   boff   = (int*)(ws + BOFF_OFF);
  float* outpre = (float*)(ws + OUTPRE_OFF);

  hipMemsetAsync(ws + ZERO_OFF, 0, ZERO_BYTES, stream);

  hipLaunchKernelGGL(k_detect, dim3(1), dim3(256), 0, stream,
                     (const unsigned int*)h, flag);
  hipLaunchKernelGGL(k_deg, dim3((N_EDGES + 255) / 256), dim3(256), 0, stream,
                     src, dst, dego, degi);
  hipLaunchKernelGGL(k_scan1, dim3(SCAN_BLOCKS), dim3(256), 0, stream,
                     dego, degi, pex, (int*)(ws + BOFF_OFF) + 0, rsqo, rsqi);
  // NOTE: bsum aliases BOFF region's first 196 ints?  NO — keep separate:
  // (bsum uses CURS region? cursor must stay zeroed for k_fill.)
  // bsum gets its own slot right after boff: see k_scan2 launch below.
  hipLaunchKernelGGL(k_scan2, dim3(1), dim3(256), 0, stream,
                     (const int*)(ws + BOFF_OFF) + 0, (int*)(ws + BOFF_OFF) + 256);
  hipLaunchKernelGGL(k_scan3, dim3(SCAN_BLOCKS), dim3(256), 0, stream,
                     pex, (const int*)(ws + BOFF_OFF) + 256, rows);
  hipLaunchKernelGGL(k_fill, dim3((N_EDGES + 255) / 256), dim3(256), 0, stream,
                     src, dst, rows, cursor, esrc);
  hipLaunchKernelGGL(k_gather, dim3(N_NODES / 4), dim3(256), 0, stream,
                     h, rows, esrc, rsqo, rsqi, flag, agg);
  hipLaunchKernelGGL(k_gemm, dim3(GEMM_BLOCKS), dim3(256), 0, stream,
                     agg, W, flag, outpre, psum, psq);
  hipLaunchKernelGGL(k_bnfinal, dim3(1), dim3(1024), 0, stream,
                     psum, psq, gamma, beta, flag, scale, shift);
  hipLaunchKernelGGL(k_rownorm, dim3(N_NODES / 4), dim3(256), 0, stream,
                     outpre, scale, shift, flag, (unsigned int*)d_out);
}

// Round 5
// 294.897 us; speedup vs baseline: 1.8021x; 1.2044x over previous
//
#include <hip/hip_runtime.h>
#include <hip/hip_bf16.h>

#define N_NODES 50000
#define N_EDGES 600000
#define GEMM_BLOCKS 784   // 256-thread blocks, 32-row tiles, <=2 tiles per block
#define SCAN_BLOCKS 196   // 196*256 = 50176 >= 50000

// ---- workspace layout (bytes) ----
#define AGG_OFF      0ull           // float[50000*128]  (fully written by k_gather)
#define DEGO_OFF     25600000ull    // int[50000]  (zeroed)
#define DEGI_OFF     25800000ull    // int[50000]  (zeroed)
#define CURS_OFF     26000000ull    // int[50000]  (zeroed)
#define ZERO_OFF     25600000ull
#define ZERO_BYTES   600000ull
#define FLAG_OFF     26200000ull    // int[1] (written by k_detect)
#define ROWS_OFF     26200064ull    // int[50001]
#define ESRC_OFF     26400128ull    // int[600000]
#define RSQO_OFF     28800128ull    // float[50000]
#define RSQI_OFF     29000128ull    // float[50000]
#define PSUM_OFF     29200192ull    // float[784*128]
#define PSQ_OFF      29724480ull    // float[784*128]
#define SCALE_OFF    30248768ull    // float[128]
#define SHIFT_OFF    30249280ull    // float[128]
#define PEX_OFF      30249792ull    // int[50176]
#define BOFF_OFF     30450496ull    // int[512]  (bsum at +0, boff at +256)
#define OUTPRE_OFF   33554432ull    // float[50000*128]

__device__ __forceinline__ float bf16lo(unsigned int v) { return __uint_as_float(v << 16); }
__device__ __forceinline__ float bf16hi(unsigned int v) { return __uint_as_float(v & 0xffff0000u); }

// ---------------- dtype detect: bf16-packed vs fp32 ----------------
__global__ __launch_bounds__(256) void k_detect(const unsigned int* __restrict__ hu,
                                                int* __restrict__ flag) {
  __shared__ int cnt;
  if (threadIdx.x == 0) cnt = 0;
  __syncthreads();
  unsigned int u = hu[threadIdx.x];
  int e = (u >> 7) & 0xFF;
  if (e >= 100 && e <= 140) atomicAdd(&cnt, 1);
  __syncthreads();
  if (threadIdx.x == 0) *flag = (cnt >= 128) ? 1 : 0;  // 1 = bf16, 0 = fp32
}

// ---------------- degrees (int atomics only) ----------------
__global__ __launch_bounds__(256) void k_deg(const int* __restrict__ src,
                                             const int* __restrict__ dst,
                                             int* __restrict__ dego,
                                             int* __restrict__ degi) {
  int e = blockIdx.x * 256 + threadIdx.x;
  if (e < N_EDGES) {
    atomicAdd(&dego[src[e]], 1);
    atomicAdd(&degi[dst[e]], 1);
  }
}

// ---------------- scan stage 1: intra-block exclusive prefix + block sums ---
__global__ __launch_bounds__(256) void k_scan1(const int* __restrict__ dego,
                                               const int* __restrict__ degi,
                                               int* __restrict__ pex,
                                               int* __restrict__ bsum,
                                               float* __restrict__ rsqo,
                                               float* __restrict__ rsqi) {
  __shared__ int ls[256];
  int t = threadIdx.x;
  int n = blockIdx.x * 256 + t;
  int d = (n < N_NODES) ? degi[n] : 0;
  ls[t] = d;
  __syncthreads();
#pragma unroll
  for (int off = 1; off < 256; off <<= 1) {
    int v = (t >= off) ? ls[t - off] : 0;
    __syncthreads();
    ls[t] += v;
    __syncthreads();
  }
  int incl = ls[t];
  if (n < N_NODES) {
    pex[n] = incl - d;
    int doo = dego[n];
    rsqi[n] = rsqrtf((float)(d   < 1 ? 1 : d));
    rsqo[n] = rsqrtf((float)(doo < 1 ? 1 : doo));
  }
  if (t == 255) bsum[blockIdx.x] = incl;
}

// ---------------- scan stage 2: scan of block sums ----------------
__global__ __launch_bounds__(256) void k_scan2(const int* __restrict__ bsum,
                                               int* __restrict__ boff) {
  __shared__ int ls[256];
  int t = threadIdx.x;
  int d = (t < SCAN_BLOCKS) ? bsum[t] : 0;
  ls[t] = d;
  __syncthreads();
#pragma unroll
  for (int off = 1; off < 256; off <<= 1) {
    int v = (t >= off) ? ls[t - off] : 0;
    __syncthreads();
    ls[t] += v;
    __syncthreads();
  }
  boff[t] = ls[t] - d;
}

// ---------------- scan stage 3: row_start = pex + boff ----------------
__global__ __launch_bounds__(256) void k_scan3(const int* __restrict__ pex,
                                               const int* __restrict__ boff,
                                               int* __restrict__ row_start) {
  int t = threadIdx.x;
  int n = blockIdx.x * 256 + t;
  if (n < N_NODES) row_start[n] = pex[n] + boff[blockIdx.x];
  if (n == 0) row_start[N_NODES] = N_EDGES;
}

// ---------------- CSR fill (int atomics only) ----------------
__global__ __launch_bounds__(256) void k_fill(const int* __restrict__ src,
                                              const int* __restrict__ dst,
                                              const int* __restrict__ row_start,
                                              int* __restrict__ cursor,
                                              int* __restrict__ esrc) {
  int e = blockIdx.x * 256 + threadIdx.x;
  if (e < N_EDGES) {
    int d = dst[e];
    int slot = atomicAdd(&cursor[d], 1);
    esrc[row_start[d] + slot] = src[e];
  }
}

// ---------------- gather: agg[n] = rsqi[n] * sum_e h[src_e]*rsqo[src_e] ----
// one wave per node; lane l covers features 2l, 2l+1; 4-edge unroll for MLP
__global__ __launch_bounds__(256) void k_gather(const void* __restrict__ hraw,
                                                const int* __restrict__ row_start,
                                                const int* __restrict__ esrc,
                                                const float* __restrict__ rsqo,
                                                const float* __restrict__ rsqi,
                                                const int* __restrict__ flag,
                                                float* __restrict__ agg) {
  int n = blockIdx.x * 4 + (threadIdx.x >> 6);   // grid = N_NODES/4 exactly
  int l = threadIdx.x & 63;
  int jb = row_start[n];
  int je = row_start[n + 1];
  float a0 = 0.f, a1 = 0.f;
  if (*flag) {
    const unsigned int* hu = (const unsigned int*)hraw;
    int j = jb;
    for (; j + 3 < je; j += 4) {
      int s0 = esrc[j], s1 = esrc[j + 1], s2 = esrc[j + 2], s3 = esrc[j + 3];
      float c0 = rsqo[s0], c1 = rsqo[s1], c2 = rsqo[s2], c3 = rsqo[s3];
      unsigned int v0 = hu[(size_t)s0 * 64 + l];
      unsigned int v1 = hu[(size_t)s1 * 64 + l];
      unsigned int v2 = hu[(size_t)s2 * 64 + l];
      unsigned int v3 = hu[(size_t)s3 * 64 + l];
      a0 += bf16lo(v0) * c0 + bf16lo(v1) * c1 + bf16lo(v2) * c2 + bf16lo(v3) * c3;
      a1 += bf16hi(v0) * c0 + bf16hi(v1) * c1 + bf16hi(v2) * c2 + bf16hi(v3) * c3;
    }
    for (; j < je; ++j) {
      int s = esrc[j];
      float c = rsqo[s];
      unsigned int v = hu[(size_t)s * 64 + l];
      a0 += bf16lo(v) * c;
      a1 += bf16hi(v) * c;
    }
  } else {
    const float2* hf = (const float2*)hraw;
    int j = jb;
    for (; j + 3 < je; j += 4) {
      int s0 = esrc[j], s1 = esrc[j + 1], s2 = esrc[j + 2], s3 = esrc[j + 3];
      float c0 = rsqo[s0], c1 = rsqo[s1], c2 = rsqo[s2], c3 = rsqo[s3];
      float2 v0 = hf[(size_t)s0 * 64 + l];
      float2 v1 = hf[(size_t)s1 * 64 + l];
      float2 v2 = hf[(size_t)s2 * 64 + l];
      float2 v3 = hf[(size_t)s3 * 64 + l];
      a0 += v0.x * c0 + v1.x * c1 + v2.x * c2 + v3.x * c3;
      a1 += v0.y * c0 + v1.y * c1 + v2.y * c2 + v3.y * c3;
    }
    for (; j < je; ++j) {
      int s = esrc[j];
      float c = rsqo[s];
      float2 v = hf[(size_t)s * 64 + l];
      a0 += v.x * c;
      a1 += v.y * c;
    }
  }
  float scn = rsqi[n];
  float2 o; o.x = a0 * scn; o.y = a1 * scn;
  *(float2*)&agg[(size_t)n * 128 + 2 * l] = o;
}

// ---------------- GEMM: outpre = agg @ W, + BN per-block partial stats ------
// 4x4 register tile per thread: block covers 32 rows x 128 cols
__global__ __launch_bounds__(256) void k_gemm(const float* __restrict__ agg,
                                              const void* __restrict__ Wraw,
                                              const int* __restrict__ flag,
                                              float* __restrict__ outpre,
                                              float* __restrict__ psum,
                                              float* __restrict__ psq) {
  __shared__ float lw[128 * 128];   // W as f32 [k][c]  (64 KB)
  __shared__ float la[32 * 128];    // 32 staged rows   (16 KB)
  int t = threadIdx.x;
  if (*flag) {
    const unsigned int* Wd = (const unsigned int*)Wraw;   // bf16 pairs
    for (int i = t; i < 8192; i += 256) {
      unsigned int v = Wd[i];
      lw[2 * i]     = bf16lo(v);
      lw[2 * i + 1] = bf16hi(v);
    }
  } else {
    const float* Wf = (const float*)Wraw;
    for (int i = t; i < 16384; i += 256) lw[i] = Wf[i];
  }

  int rg = t >> 5;       // 0..7  -> rows rb..rb+3
  int cg = t & 31;       // 0..31 -> cols cb..cb+3
  int rb = rg * 4;
  int cb = cg * 4;
  float s1[4] = {0.f, 0.f, 0.f, 0.f};
  float s2[4] = {0.f, 0.f, 0.f, 0.f};

  __syncthreads();

  for (int r0 = blockIdx.x * 32; r0 < N_NODES; r0 += GEMM_BLOCKS * 32) {
    // stage 32 rows of agg (zeros for OOB rows -> exact stats)
    for (int i = t; i < 1024; i += 256) {
      int row = i >> 5;
      int c4  = (i & 31) * 4;
      int r   = r0 + row;
      float4 v;
      if (r < N_NODES) v = *(const float4*)&agg[(size_t)r * 128 + c4];
      else             v = make_float4(0.f, 0.f, 0.f, 0.f);
      *(float4*)&la[row * 128 + c4] = v;
    }
    __syncthreads();

    float acc[4][4];
#pragma unroll
    for (int i = 0; i < 4; ++i)
#pragma unroll
      for (int jj = 0; jj < 4; ++jj) acc[i][jj] = 0.f;

    for (int k = 0; k < 128; k += 4) {
      float4 w0 = *(const float4*)&lw[(k + 0) * 128 + cb];
      float4 w1 = *(const float4*)&lw[(k + 1) * 128 + cb];
      float4 w2 = *(const float4*)&lw[(k + 2) * 128 + cb];
      float4 w3 = *(const float4*)&lw[(k + 3) * 128 + cb];
#pragma unroll
      for (int i = 0; i < 4; ++i) {
        float4 a = *(const float4*)&la[(rb + i) * 128 + k];
        acc[i][0] += a.x * w0.x + a.y * w1.x + a.z * w2.x + a.w * w3.x;
        acc[i][1] += a.x * w0.y + a.y * w1.y + a.z * w2.y + a.w * w3.y;
        acc[i][2] += a.x * w0.z + a.y * w1.z + a.z * w2.z + a.w * w3.z;
        acc[i][3] += a.x * w0.w + a.y * w1.w + a.z * w2.w + a.w * w3.w;
      }
    }

#pragma unroll
    for (int i = 0; i < 4; ++i) {
      int r = r0 + rb + i;
      if (r < N_NODES) {
        float4 o; o.x = acc[i][0]; o.y = acc[i][1]; o.z = acc[i][2]; o.w = acc[i][3];
        *(float4*)&outpre[(size_t)r * 128 + cb] = o;
      }
#pragma unroll
      for (int jj = 0; jj < 4; ++jj) {
        s1[jj] += acc[i][jj];
        s2[jj] += acc[i][jj] * acc[i][jj];
      }
    }
    __syncthreads();
  }

  // reduce BN partials across the 8 row-groups (reuse la)
  float* sred = la;
#pragma unroll
  for (int jj = 0; jj < 4; ++jj) sred[rg * 128 + cb + jj] = s1[jj];
  __syncthreads();
  if (t < 128) {
    float v = 0.f;
#pragma unroll
    for (int g = 0; g < 8; ++g) v += sred[g * 128 + t];
    psum[blockIdx.x * 128 + t] = v;
  }
  __syncthreads();
#pragma unroll
  for (int jj = 0; jj < 4; ++jj) sred[rg * 128 + cb + jj] = s2[jj];
  __syncthreads();
  if (t < 128) {
    float v = 0.f;
#pragma unroll
    for (int g = 0; g < 8; ++g) v += sred[g * 128 + t];
    psq[blockIdx.x * 128 + t] = v;
  }
}

// ---------------- BN finalize: reduce 784 partials -> scale/shift -----------
__global__ __launch_bounds__(1024) void k_bnfinal(const float* __restrict__ psum,
                                                  const float* __restrict__ psq,
                                                  const void* __restrict__ gamma,
                                                  const void* __restrict__ beta,
                                                  const int* __restrict__ flag,
                                                  float* __restrict__ scale,
                                                  float* __restrict__ shift) {
  __shared__ float r1[1024], r2[1024];
  int t = threadIdx.x;
  int c = t & 127;
  int j = t >> 7;           // 0..7
  float s1 = 0.f, s2 = 0.f;
  for (int b = j; b < GEMM_BLOCKS; b += 8) {
    s1 += psum[b * 128 + c];
    s2 += psq [b * 128 + c];
  }
  r1[t] = s1; r2[t] = s2;
  __syncthreads();
  if (j == 0) {
#pragma unroll
    for (int jj = 1; jj < 8; ++jj) { s1 += r1[c + 128 * jj]; s2 += r2[c + 128 * jj]; }
    const float invN = 1.0f / (float)N_NODES;
    float mu  = s1 * invN;
    float var = s2 * invN - mu * mu;
    float is  = rsqrtf(var + 1e-5f);
    float g, b;
    if (*flag) {
      g = __bfloat162float(((const __hip_bfloat16*)gamma)[c]);
      b = __bfloat162float(((const __hip_bfloat16*)beta)[c]);
    } else {
      g = ((const float*)gamma)[c];
      b = ((const float*)beta)[c];
    }
    scale[c] = g * is;
    shift[c] = b - mu * g * is;
  }
}

// ---------------- BN apply + ReLU + row L2 normalize + store ----------------
__global__ __launch_bounds__(256) void k_rownorm(const float* __restrict__ outpre,
                                                 const float* __restrict__ scale,
                                                 const float* __restrict__ shift,
                                                 const int* __restrict__ flag,
                                                 void* __restrict__ outraw) {
  int r = blockIdx.x * 4 + (threadIdx.x >> 6);   // grid = N_NODES/4 exactly
  int l = threadIdx.x & 63;
  float2 x  = *(const float2*)&outpre[(size_t)r * 128 + 2 * l];
  float2 sc = *(const float2*)&scale[2 * l];
  float2 sh = *(const float2*)&shift[2 * l];
  float y0 = fmaxf(x.x * sc.x + sh.x, 0.f);
  float y1 = fmaxf(x.y * sc.y + sh.y, 0.f);
  float ss = y0 * y0 + y1 * y1;
#pragma unroll
  for (int o = 1; o < 64; o <<= 1) ss += __shfl_xor(ss, o, 64);
  float inv = 1.0f / fmaxf(sqrtf(ss), 1e-12f);
  y0 *= inv; y1 *= inv;
  if (*flag) {
    __hip_bfloat162 o2;
    o2.x = __float2bfloat16(y0);
    o2.y = __float2bfloat16(y1);
    union { __hip_bfloat162 v; unsigned int u; } cvt;
    cvt.v = o2;
    ((unsigned int*)outraw)[(size_t)r * 64 + l] = cvt.u;
  } else {
    float2 o2; o2.x = y0; o2.y = y1;
    ((float2*)outraw)[(size_t)r * 64 + l] = o2;
  }
}

extern "C" void kernel_launch(void* const* d_in, const int* in_sizes, int n_in,
                              void* d_out, int out_size, void* d_ws, size_t ws_size,
                              hipStream_t stream) {
  const void* h     = d_in[0];
  const void* W     = d_in[1];
  const void* gamma = d_in[2];
  const void* beta  = d_in[3];
  const int*  src   = (const int*)d_in[4];
  const int*  dst   = (const int*)d_in[5];

  char* ws = (char*)d_ws;
  float* agg    = (float*)(ws + AGG_OFF);
  int*   dego   = (int*)(ws + DEGO_OFF);
  int*   degi   = (int*)(ws + DEGI_OFF);
  int*   cursor = (int*)(ws + CURS_OFF);
  int*   flag   = (int*)(ws + FLAG_OFF);
  int*   rows   = (int*)(ws + ROWS_OFF);
  int*   esrc   = (int*)(ws + ESRC_OFF);
  float* rsqo   = (float*)(ws + RSQO_OFF);
  float* rsqi   = (float*)(ws + RSQI_OFF);
  float* psum   = (float*)(ws + PSUM_OFF);
  float* psq    = (float*)(ws + PSQ_OFF);
  float* scale  = (float*)(ws + SCALE_OFF);
  float* shift  = (float*)(ws + SHIFT_OFF);
  int*   pex    = (int*)(ws + PEX_OFF);
  float* outpre = (float*)(ws + OUTPRE_OFF);

  hipMemsetAsync(ws + ZERO_OFF, 0, ZERO_BYTES, stream);

  hipLaunchKernelGGL(k_detect, dim3(1), dim3(256), 0, stream,
                     (const unsigned int*)h, flag);
  hipLaunchKernelGGL(k_deg, dim3((N_EDGES + 255) / 256), dim3(256), 0, stream,
                     src, dst, dego, degi);
  hipLaunchKernelGGL(k_scan1, dim3(SCAN_BLOCKS), dim3(256), 0, stream,
                     dego, degi, pex, (int*)(ws + BOFF_OFF) + 0, rsqo, rsqi);
  hipLaunchKernelGGL(k_scan2, dim3(1), dim3(256), 0, stream,
                     (const int*)(ws + BOFF_OFF) + 0, (int*)(ws + BOFF_OFF) + 256);
  hipLaunchKernelGGL(k_scan3, dim3(SCAN_BLOCKS), dim3(256), 0, stream,
                     pex, (const int*)(ws + BOFF_OFF) + 256, rows);
  hipLaunchKernelGGL(k_fill, dim3((N_EDGES + 255) / 256), dim3(256), 0, stream,
                     src, dst, rows, cursor, esrc);
  hipLaunchKernelGGL(k_gather, dim3(N_NODES / 4), dim3(256), 0, stream,
                     h, rows, esrc, rsqo, rsqi, flag, agg);
  hipLaunchKernelGGL(k_gemm, dim3(GEMM_BLOCKS), dim3(256), 0, stream,
                     agg, W, flag, outpre, psum, psq);
  hipLaunchKernelGGL(k_bnfinal, dim3(1), dim3(1024), 0, stream,
                     psum, psq, gamma, beta, flag, scale, shift);
  hipLaunchKernelGGL(k_rownorm, dim3(N_NODES / 4), dim3(256), 0, stream,
                     outpre, scale, shift, flag, (unsigned int*)d_out);
}